// Round 4
// baseline (565.929 us; speedup 1.0000x reference)
//
#include <hip/hip_runtime.h>

namespace {

constexpr int T_STEPS = 1000;
constexpr int NB      = 4096;
constexpr float LOG2E = 1.4426950408889634f;

__device__ __forceinline__ float fexp2(float x) { return __builtin_amdgcn_exp2f(x); }
__device__ __forceinline__ float frcp(float x)  { return __builtin_amdgcn_rcpf(x); }

// DPP cross-lane on the VALU pipe. quad_perm 0x00-0xFF: dest lane k (in quad)
// <- src lane perm[k]. row_ror 0x120|N: rotate within each 16-lane row.
template<int CTRL>
__device__ __forceinline__ float dppf(float v) {
    int i = __float_as_int(v);
    return __int_as_float(__builtin_amdgcn_update_dpp(i, i, CTRL, 0xF, 0xF, false));
}
// xor-16 within each 32-lane half: BitMode offset = (xor<<10)|(or<<5)|and
__device__ __forceinline__ float swzx16(float v) {
    return __int_as_float(__builtin_amdgcn_ds_swizzle(__float_as_int(v), 0x401F));
}

// One element per 32 lanes (2 elements/wave, 2048 waves = 2 waves/SIMD).
// Lane q in [0,32): 16-row R=q>>4, j=q&15, quad qd=j>>2, gate g=q&3.
// unit u = R*4+qd; lane owns weight row = g*8+u (gate order i,f,g,o).
// All 4 lanes of a quad redundantly compute the same c/h for their unit.
// Cross-lane: 3 quad_perm (gate gather) + 1 ds_swizzle xor16 + 6 row_ror
// (h broadcast) per layer. No LDS storage, no barriers.
__global__ __launch_bounds__(256, 2)
void lstm_fused_kernel(
    const float* __restrict__ state, const float* __restrict__ dist,
    const float* __restrict__ e1W1, const float* __restrict__ e1b1,
    const float* __restrict__ e1W2, const float* __restrict__ e1b2,
    const float* __restrict__ e2W1, const float* __restrict__ e2b1,
    const float* __restrict__ e2W2, const float* __restrict__ e2b2,
    const float* __restrict__ Wih0, const float* __restrict__ Whh0,
    const float* __restrict__ bih0, const float* __restrict__ bhh0,
    const float* __restrict__ Wih1, const float* __restrict__ Whh1,
    const float* __restrict__ bih1, const float* __restrict__ bhh1,
    const float* __restrict__ decW, const float* __restrict__ decb,
    const float* __restrict__ finW, const float* __restrict__ finb,
    const float* __restrict__ fin2W, const float* __restrict__ fin2b,
    float* __restrict__ out)
{
    const int tid = (int)threadIdx.x;
    const int q   = tid & 31;
    const int n   = blockIdx.x * 8 + (tid >> 5);
    const int j   = q & 15;        // lane in 16-row
    const int R   = q >> 4;        // which 16-row of the group
    const int qd  = j >> 2;        // quad in row = unit-in-row
    const int g   = q & 3;         // gate (i,f,g,o)
    const int u   = R * 4 + qd;    // unit
    const int row = g * 8 + u;     // gate-matrix row

    // --- probe row_ror direction once: slot k of h = unit-in-row (qd + sgn*k)&3 ---
    const int pv  = __builtin_amdgcn_update_dpp(0, j, 0x121 /*row_ror:1*/, 0xF, 0xF, true);
    const int sgn = (pv == ((j + 1) & 15)) ? 1 : -1;
    auto pidx = [&](int k) {       // h-slot k in [0,8) -> unit index
        const int rsel = (k < 4) ? R : (1 - R);
        return rsel * 4 + ((qd + sgn * (k & 3)) & 3);
    };

    // activation constants (tanh lane iff g==2); fold exp2 scale into weights
    const bool isG = (g == 2);
    const float scl = isG ? (-2.0f * LOG2E) : (-LOG2E);
    const float mul = isG ? 2.0f : 1.0f;
    const float add = isG ? -1.0f : 0.0f;
    const bool gb0 = (g & 1) != 0;
    const bool gb1 = (g & 2) != 0;

    // ---- per-lane weight row (h-side permuted to the rotated slot layout) ----
    float wx0[8], wh0[8], wx1[8], wh1[8];
#pragma unroll
    for (int k = 0; k < 8; ++k) {
        const int p = pidx(k);
        wx0[k] = Wih0[row * 8 + k] * scl; wh0[k] = Whh0[row * 8 + p] * scl;
        wx1[k] = Wih1[row * 8 + p] * scl; wh1[k] = Whh1[row * 8 + p] * scl;
    }
    const float b0 = (bih0[row] + bhh0[row]) * scl;
    const float b1 = (bih1[row] + bhh1[row]) * scl;

    // decoder: lane holds dec row dr=g (h-permuted); head: quad parity 0=mu 1=sigma
    const int dr = g;
    const int hsel = (q >> 2) & 1;
    float dwr[8];
#pragma unroll
    for (int k = 0; k < 8; ++k) dwr[k] = decW[dr * 8 + pidx(k)];
    const float db = decb[dr];
    float fwp[4]; float fb;
    {
        const float* Wp = hsel ? fin2W : finW;
        const float* bp = hsel ? fin2b : finb;
#pragma unroll
        for (int jj = 0; jj < 4; ++jj) fwp[jj] = Wp[dr * 4 + ((dr + jj) & 3)];
        fb = bp[dr];
    }

    // ---------------- encoders (one-time, replicated per lane) ----------------
    float h0r[8], h1r[8], c0, c1;
    {
        float s[16];
#pragma unroll
        for (int k = 0; k < 16; ++k) s[k] = state[n * 16 + k];
        float hm1[4], hm2[4];
#pragma unroll
        for (int m = 0; m < 4; ++m) {
            float a = e1b1[m], b = e2b1[m];
#pragma unroll
            for (int k = 0; k < 16; ++k) {
                a = fmaf(s[k], e1W1[m * 16 + k], a);
                b = fmaf(s[k], e2W1[m * 16 + k], b);
            }
            hm1[m] = fmaxf(a, 0.0f); hm2[m] = fmaxf(b, 0.0f);
        }
#pragma unroll
        for (int k = 0; k < 8; ++k) {
            const int p = pidx(k);
            float a = e1b2[p], b = e1b2[8 + p];
#pragma unroll
            for (int m = 0; m < 4; ++m) {
                a = fmaf(hm1[m], e1W2[p * 4 + m], a);
                b = fmaf(hm1[m], e1W2[(8 + p) * 4 + m], b);
            }
            h0r[k] = fmaxf(a, 0.0f);   // layer0 h init (slot layout)
            h1r[k] = fmaxf(b, 0.0f);   // layer1 h init
        }
        float a = e2b2[u], b = e2b2[8 + u];
#pragma unroll
        for (int m = 0; m < 4; ++m) {
            a = fmaf(hm2[m], e2W2[u * 4 + m], a);
            b = fmaf(hm2[m], e2W2[(8 + u) * 4 + m], b);
        }
        c0 = fmaxf(a, 0.0f);
        c1 = fmaxf(b, 0.0f);
    }

    // ---------------- x stream + output pointer ----------------
    const float4* dp = reinterpret_cast<const float4*>(dist) + (size_t)n * 2;
    constexpr size_t TS4 = (size_t)NB * 2;
    float* outp = out + (size_t)hsel * T_STEPS * NB * 4 + (size_t)n * 4 + dr;
    const bool doStore = (q < 8);

    auto step = [&](const float4& lo, const float4& hi, float* op) {
        const float x[8] = {lo.x, lo.y, lo.z, lo.w, hi.x, hi.y, hi.z, hi.w};
        // ----- layer 0 -----
        float ax = b0, ah = 0.0f;
#pragma unroll
        for (int k = 0; k < 8; ++k) { ax = fmaf(x[k], wx0[k], ax); ah = fmaf(h0r[k], wh0[k], ah); }
        float v = fmaf(frcp(1.0f + fexp2(ax + ah)), mul, add);   // sig | tanh per gate
        float xq1 = dppf<0xB1>(v);   // gate g^1
        float xq2 = dppf<0x4E>(v);   // gate g^2
        float xq3 = dppf<0x1B>(v);   // gate g^3
        float t1 = v * xq2, t2 = xq1 * xq3;
        float P  = gb0 ? t2 : t1;            // sig(i)*tanh(g)
        float S1 = gb0 ? xq2 : xq3;
        float S2 = gb0 ? v   : xq1;
        float sf = gb1 ? S1 : S2;            // sig(f)
        float so = gb1 ? S2 : S1;            // sig(o)
        c0 = fmaf(sf, c0, P);
        float th = fmaf(frcp(1.0f + fexp2(c0 * (-2.0f * LOG2E))), 2.0f, -1.0f);
        float hu = so * th;                  // identical across the quad
        float hsw = swzx16(hu);
        h0r[0] = hu;  h0r[1] = dppf<0x124>(hu);  h0r[2] = dppf<0x128>(hu);  h0r[3] = dppf<0x12C>(hu);
        h0r[4] = hsw; h0r[5] = dppf<0x124>(hsw); h0r[6] = dppf<0x128>(hsw); h0r[7] = dppf<0x12C>(hsw);
        // ----- layer 1 (own-h first; h0 slots 4-7, which depend on the swizzle, last) -----
        ax = b1; ah = 0.0f;
#pragma unroll
        for (int k = 0; k < 8; ++k) ah = fmaf(h1r[k], wh1[k], ah);
#pragma unroll
        for (int k = 0; k < 8; ++k) ax = fmaf(h0r[k], wx1[k], ax);
        v = fmaf(frcp(1.0f + fexp2(ax + ah)), mul, add);
        xq1 = dppf<0xB1>(v); xq2 = dppf<0x4E>(v); xq3 = dppf<0x1B>(v);
        t1 = v * xq2; t2 = xq1 * xq3;
        P  = gb0 ? t2 : t1;
        S1 = gb0 ? xq2 : xq3;
        S2 = gb0 ? v   : xq1;
        sf = gb1 ? S1 : S2;
        so = gb1 ? S2 : S1;
        c1 = fmaf(sf, c1, P);
        th = fmaf(frcp(1.0f + fexp2(c1 * (-2.0f * LOG2E))), 2.0f, -1.0f);
        hu = so * th;
        hsw = swzx16(hu);
        h1r[0] = hu;  h1r[1] = dppf<0x124>(hu);  h1r[2] = dppf<0x128>(hu);  h1r[3] = dppf<0x12C>(hu);
        h1r[4] = hsw; h1r[5] = dppf<0x124>(hsw); h1r[6] = dppf<0x128>(hsw); h1r[7] = dppf<0x12C>(hsw);
        // ----- decoder + heads (quad_perm rotations, HW-proven orientation) -----
        float da = db;
#pragma unroll
        for (int k = 0; k < 8; ++k) da = fmaf(h1r[k], dwr[k], da);
        da = fmaxf(da, 0.0f);
        const float d1 = dppf<0x39>(da);  // dec[(dr+1)&3]
        const float d2 = dppf<0x4E>(da);  // dec[(dr+2)&3]
        const float d3 = dppf<0x93>(da);  // dec[(dr+3)&3]
        float o = fb;
        o = fmaf(da, fwp[0], o); o = fmaf(d1, fwp[1], o);
        o = fmaf(d2, fwp[2], o); o = fmaf(d3, fwp[3], o);
        if (doStore) *op = o;
    };

    // prologue: t=0,1 in regs; hot loop prefetches unconditionally (tail peeled)
    float4 xA0 = dp[0],   xA1 = dp[1];
    float4 xB0 = dp[TS4], xB1 = dp[TS4 + 1];
    const float4* pf = dp + 2 * TS4;

    for (int it = 0; it < (T_STEPS / 2) - 1; ++it) {
        float4 nA0 = pf[0], nA1 = pf[1];
        step(xA0, xA1, outp);
        outp += (size_t)NB * 4;
        float4 nB0 = pf[TS4], nB1 = pf[TS4 + 1];
        step(xB0, xB1, outp);
        outp += (size_t)NB * 4;
        xA0 = nA0; xA1 = nA1; xB0 = nB0; xB1 = nB1;
        pf += 2 * TS4;
    }
    step(xA0, xA1, outp);
    outp += (size_t)NB * 4;
    step(xB0, xB1, outp);
}

} // namespace

extern "C" void kernel_launch(void* const* d_in, const int* in_sizes, int n_in,
                              void* d_out, int out_size, void* d_ws, size_t ws_size,
                              hipStream_t stream) {
    const float* state = (const float*)d_in[0];
    const float* dist  = (const float*)d_in[1];
    const float* e1W1  = (const float*)d_in[2];
    const float* e1b1  = (const float*)d_in[3];
    const float* e1W2  = (const float*)d_in[4];
    const float* e1b2  = (const float*)d_in[5];
    const float* e2W1  = (const float*)d_in[6];
    const float* e2b1  = (const float*)d_in[7];
    const float* e2W2  = (const float*)d_in[8];
    const float* e2b2  = (const float*)d_in[9];
    const float* Wih0  = (const float*)d_in[10];
    const float* Whh0  = (const float*)d_in[11];
    const float* bih0  = (const float*)d_in[12];
    const float* bhh0  = (const float*)d_in[13];
    const float* Wih1  = (const float*)d_in[14];
    const float* Whh1  = (const float*)d_in[15];
    const float* bih1  = (const float*)d_in[16];
    const float* bhh1  = (const float*)d_in[17];
    const float* decW  = (const float*)d_in[18];
    const float* decb  = (const float*)d_in[19];
    const float* finW  = (const float*)d_in[20];
    const float* finb  = (const float*)d_in[21];
    const float* fin2W = (const float*)d_in[22];
    const float* fin2b = (const float*)d_in[23];
    float* outp = (float*)d_out;

    lstm_fused_kernel<<<dim3(NB / 8), dim3(256), 0, stream>>>(
        state, dist,
        e1W1, e1b1, e1W2, e1b2,
        e2W1, e2b1, e2W2, e2b2,
        Wih0, Whh0, bih0, bhh0,
        Wih1, Whh1, bih1, bhh1,
        decW, decb, finW, finb, fin2W, fin2b,
        outp);
}

// Round 5
// 528.163 us; speedup vs baseline: 1.0715x; 1.0715x over previous
//
#include <hip/hip_runtime.h>

namespace {

constexpr int T_STEPS = 1000;
constexpr int NB      = 4096;
constexpr float LOG2E = 1.4426950408889634f;

__device__ __forceinline__ float fexp2(float x) { return __builtin_amdgcn_exp2f(x); }
__device__ __forceinline__ float frcp(float x)  { return __builtin_amdgcn_rcpf(x); }

// DPP on the VALU pipe. row_ror 0x120|N rotates within each 16-lane row;
// quad_perm 0x00-0xFF permutes within quads.
template<int CTRL>
__device__ __forceinline__ float dppf(float v) {
    int i = __float_as_int(v);
    return __int_as_float(__builtin_amdgcn_update_dpp(i, i, CTRL, 0xF, 0xF, false));
}

// v_permlane32_swap_b32 (gfx950, VALU): swaps lanes[32:63] of vdst with
// lanes[0:31] of src. r[0] = new vdst = { a (lanes<32) | b[lane-32] (lanes>=32) }.
// Directed lower->upper transfer with lower keeping its own value.
__device__ __forceinline__ float xlow(float a, float b) {
    auto r = __builtin_amdgcn_permlane32_swap(__float_as_int(a), __float_as_int(b),
                                              false, false);
    return __int_as_float(r[0]);
}

// Layer-pipelined LSTM: one element = 32 lanes spread across the two wave
// halves. Lanes 0-31: LSTM layer 0 at body i; lanes 32-63: layer 1 at body
// i-1 (one step behind), same instruction stream. One body = ONE layer pass,
// so the per-step dependency chain is half of the sequential 2-layer version.
// Within each 16-lane group: round-3-proven row scheme (q: u=q&7, hlf=q>>3;
// lane computes gate rows r0=hlf*16+u, r1=r0+8), DPP-only cross-lane.
// The h0 -> layer-1 handoff is v_permlane32_swap (VALU). Zero LDS ops.
__global__ __launch_bounds__(256, 2)
void lstm_fused_kernel(
    const float* __restrict__ state, const float* __restrict__ dist,
    const float* __restrict__ e1W1, const float* __restrict__ e1b1,
    const float* __restrict__ e1W2, const float* __restrict__ e1b2,
    const float* __restrict__ e2W1, const float* __restrict__ e2b1,
    const float* __restrict__ e2W2, const float* __restrict__ e2b2,
    const float* __restrict__ Wih0, const float* __restrict__ Whh0,
    const float* __restrict__ bih0, const float* __restrict__ bhh0,
    const float* __restrict__ Wih1, const float* __restrict__ Whh1,
    const float* __restrict__ bih1, const float* __restrict__ bhh1,
    const float* __restrict__ decW, const float* __restrict__ decb,
    const float* __restrict__ finW, const float* __restrict__ finb,
    const float* __restrict__ fin2W, const float* __restrict__ fin2b,
    float* __restrict__ out)
{
    const int tid = (int)threadIdx.x;
    const int q   = tid & 15;                  // lane in 16-group
    const int lay = (tid >> 5) & 1;            // wave half: 0=layer0, 1=layer1
    const int n   = blockIdx.x * 8 + (tid >> 6) * 2 + ((tid >> 4) & 1);
    const int u   = q & 7;
    const int hlf = q >> 3;
    const int r0  = hlf * 16 + u;              // row A (i_u | g_u)
    const int r1  = r0 + 8;                    // row B (f_u | o_u)

    // --- probe row_ror direction once (round-3 proven): slot k holds h[(u+sgn*k)&7]
    const int pv  = __builtin_amdgcn_update_dpp(0, q, 0x121, 0xF, 0xF, true);
    const int sgn = (pv == ((q + 1) & 15)) ? 1 : -1;
    auto pidx = [&](int k) { return (u + sgn * k) & 7; };

    // activation constants; exp2 scale folded into weights/biases
    const float sA   = hlf ? (-2.0f * LOG2E) : (-LOG2E);   // row A: sigmoid | tanh
    const float sB   = -LOG2E;                              // row B always sigmoid
    const float mulA = hlf ? 2.0f : 1.0f;
    const float addA = hlf ? -1.0f : 0.0f;

    // ---- this half's layer weights (x-cols natural for layer0, slot-permuted
    //      for layer1 since its input is the h0 slot vector; h-cols slot-permuted)
    const float* Wih = lay ? Wih1 : Wih0;
    const float* Whh = lay ? Whh1 : Whh0;
    const float* bih = lay ? bih1 : bih0;
    const float* bhh = lay ? bhh1 : bhh0;
    float wxa[8], wha[8], wxb[8], whb[8];
#pragma unroll
    for (int k = 0; k < 8; ++k) {
        const int p  = pidx(k);
        const int xc = lay ? p : k;
        wxa[k] = Wih[r0 * 8 + xc] * sA; wha[k] = Whh[r0 * 8 + p] * sA;
        wxb[k] = Wih[r1 * 8 + xc] * sB; whb[k] = Whh[r1 * 8 + p] * sB;
    }
    const float bA = (bih[r0] + bhh[r0]) * sA;
    const float bB = (bih[r1] + bhh[r1]) * sB;

    // decoder (meaningful on upper half; all lanes run it in lockstep)
    const int dr = q & 3;
    float dwr[8];
#pragma unroll
    for (int k = 0; k < 8; ++k) dwr[k] = decW[dr * 8 + pidx(k)];
    const float db = decb[dr];
    float fwp[4]; float fb;
    {
        const float* Wp = (u < 4) ? finW : fin2W;
        const float* bp = (u < 4) ? finb : fin2b;
        const int oo = u & 3;
#pragma unroll
        for (int jj = 0; jj < 4; ++jj) fwp[jj] = Wp[oo * 4 + ((dr + jj) & 3)];
        fb = bp[oo];
    }

    // ---------------- encoders: this half's layer h/c init ----------------
    float hr[8], c;
    {
        float s[16];
#pragma unroll
        for (int k = 0; k < 16; ++k) s[k] = state[n * 16 + k];
        float hm1[4], hm2[4];
#pragma unroll
        for (int m = 0; m < 4; ++m) {
            float a = e1b1[m], b = e2b1[m];
#pragma unroll
            for (int k = 0; k < 16; ++k) {
                a = fmaf(s[k], e1W1[m * 16 + k], a);
                b = fmaf(s[k], e2W1[m * 16 + k], b);
            }
            hm1[m] = fmaxf(a, 0.0f); hm2[m] = fmaxf(b, 0.0f);
        }
        const int off = lay * 8;
#pragma unroll
        for (int k = 0; k < 8; ++k) {
            const int p = pidx(k);
            float a = e1b2[off + p];
#pragma unroll
            for (int m = 0; m < 4; ++m) a = fmaf(hm1[m], e1W2[(off + p) * 4 + m], a);
            hr[k] = fmaxf(a, 0.0f);            // own layer h init, slot layout
        }
        float cc = e2b2[off + u];
#pragma unroll
        for (int m = 0; m < 4; ++m) cc = fmaf(hm2[m], e2W2[(off + u) * 4 + m], cc);
        c = fmaxf(cc, 0.0f);                   // own layer c init
    }

    // ---------------- x stream + output pointer ----------------
    const float4* dp = reinterpret_cast<const float4*>(dist) + (size_t)n * 2;
    constexpr size_t TS4 = (size_t)NB * 2;     // float4 stride per timestep
    float* outp = out + ((u < 4) ? ((size_t)n * 4 + u)
                                 : ((size_t)T_STEPS * NB * 4 + (size_t)n * 4 + (u - 4)));
    const bool doStore = (lay == 1) && (q < 8);

    // one body = one layer pass + decoder. maskUp: keep upper state (body 0).
    auto body = [&](const float4& lo, const float4& hi, float* op,
                    bool maskUp, bool doSt) {
        const float xld[8] = {lo.x, lo.y, lo.z, lo.w, hi.x, hi.y, hi.z, hi.w};
        float xin[8];
#pragma unroll
        for (int k = 0; k < 8; ++k) xin[k] = xlow(xld[k], hr[k]);  // upper <- lower h0 slots
        float xa0 = bA, xa1 = 0.0f, ha0 = 0.0f, ha1 = 0.0f;
        float xb0 = bB, xb1 = 0.0f, hb0 = 0.0f, hb1 = 0.0f;
#pragma unroll
        for (int k = 0; k < 4; ++k) {          // 2-way split chains (shorter dep depth)
            xa0 = fmaf(xin[k],     wxa[k],     xa0);
            xa1 = fmaf(xin[4 + k], wxa[4 + k], xa1);
            ha0 = fmaf(hr[k],      wha[k],     ha0);
            ha1 = fmaf(hr[4 + k],  wha[4 + k], ha1);
            xb0 = fmaf(xin[k],     wxb[k],     xb0);
            xb1 = fmaf(xin[4 + k], wxb[4 + k], xb1);
            hb0 = fmaf(hr[k],      whb[k],     hb0);
            hb1 = fmaf(hr[4 + k],  whb[4 + k], hb1);
        }
        const float A = (xa0 + xa1) + (ha0 + ha1);
        const float B = (xb0 + xb1) + (hb0 + hb1);
        float a0 = fmaf(frcp(1.0f + fexp2(A)), mulA, addA);  // sig(i)|tanh(g)
        float a1 = frcp(1.0f + fexp2(B));                     // sig(f)|sig(o)
        float s0 = dppf<0x128>(a0);            // xor-8 partner (round-3 proven)
        float s1 = dppf<0x128>(a1);
        float prod = a0 * s0;                  // sig(i)*tanh(g) on both halves
        float fg = hlf ? s1 : a1;
        float og = hlf ? a1 : s1;
        float cn = fmaf(fg, c, prod);
        float th = fmaf(frcp(1.0f + fexp2(cn * (-2.0f * LOG2E))), 2.0f, -1.0f);
        float hn = og * th;
        if (maskUp) {                          // body 0: upper half keeps init state
            cn = lay ? c     : cn;
            hn = lay ? hr[0] : hn;             // slot 0 = own-unit h
        }
        c = cn;
        hr[0] = hn;
        hr[1] = dppf<0x121>(hn); hr[2] = dppf<0x122>(hn); hr[3] = dppf<0x123>(hn);
        hr[4] = dppf<0x124>(hn); hr[5] = dppf<0x125>(hn); hr[6] = dppf<0x126>(hn);
        hr[7] = dppf<0x127>(hn);
        // decoder + heads on the fresh h (upper half = h1 of step i-1)
        float da0 = db, da1 = 0.0f;
#pragma unroll
        for (int k = 0; k < 4; ++k) {
            da0 = fmaf(hr[k],     dwr[k],     da0);
            da1 = fmaf(hr[4 + k], dwr[4 + k], da1);
        }
        float da = fmaxf(da0 + da1, 0.0f);
        const float d1 = dppf<0x39>(da);
        const float d2 = dppf<0x4E>(da);
        const float d3 = dppf<0x93>(da);
        float o = fb;
        o = fmaf(da, fwp[0], o); o = fmaf(d1, fwp[1], o);
        o = fmaf(d2, fwp[2], o); o = fmaf(d3, fwp[3], o);
        if (doSt && doStore) *op = o;
    };

    // prologue: x0,x1 in regs
    float4 A0 = dp[0],   A1 = dp[1];
    float4 B0 = dp[TS4], B1 = dp[TS4 + 1];
    const float4* pf = dp + 2 * TS4;           // t = 2

    // body 0: lower does step 0; upper idles (masked), no store
    {
        float4 n0 = pf[0], n1 = pf[1]; pf += TS4;   // prefetch t=2 -> A
        body(A0, A1, nullptr, true, false);
        A0 = n0; A1 = n1;
    }
    // main loop: bodies 1..998 (consume x1..x998), store steps 0..997
    for (int it = 0; it < 499; ++it) {
        float4 n0 = pf[0], n1 = pf[1]; pf += TS4;   // t = 2it+3 -> B
        body(B0, B1, outp, false, true); outp += (size_t)NB * 4;
        B0 = n0; B1 = n1;
        const float4* p2 = (it == 498) ? (dp + (size_t)(T_STEPS - 1) * TS4) : pf;
        float4 m0 = p2[0], m1 = p2[1]; pf += TS4;   // t = 2it+4 -> A (clamped)
        body(A0, A1, outp, false, true); outp += (size_t)NB * 4;
        A0 = m0; A1 = m1;
    }
    // body 999: consume x999, store step 998
    body(B0, B1, outp, false, true); outp += (size_t)NB * 4;
    // drain: upper processes h0(999) -> stores step 999 (lower result dead)
    body(B0, B1, outp, false, true);
}

} // namespace

extern "C" void kernel_launch(void* const* d_in, const int* in_sizes, int n_in,
                              void* d_out, int out_size, void* d_ws, size_t ws_size,
                              hipStream_t stream) {
    const float* state = (const float*)d_in[0];
    const float* dist  = (const float*)d_in[1];
    const float* e1W1  = (const float*)d_in[2];
    const float* e1b1  = (const float*)d_in[3];
    const float* e1W2  = (const float*)d_in[4];
    const float* e1b2  = (const float*)d_in[5];
    const float* e2W1  = (const float*)d_in[6];
    const float* e2b1  = (const float*)d_in[7];
    const float* e2W2  = (const float*)d_in[8];
    const float* e2b2  = (const float*)d_in[9];
    const float* Wih0  = (const float*)d_in[10];
    const float* Whh0  = (const float*)d_in[11];
    const float* bih0  = (const float*)d_in[12];
    const float* bhh0  = (const float*)d_in[13];
    const float* Wih1  = (const float*)d_in[14];
    const float* Whh1  = (const float*)d_in[15];
    const float* bih1  = (const float*)d_in[16];
    const float* bhh1  = (const float*)d_in[17];
    const float* decW  = (const float*)d_in[18];
    const float* decb  = (const float*)d_in[19];
    const float* finW  = (const float*)d_in[20];
    const float* finb  = (const float*)d_in[21];
    const float* fin2W = (const float*)d_in[22];
    const float* fin2b = (const float*)d_in[23];
    float* outp = (float*)d_out;

    lstm_fused_kernel<<<dim3(NB / 8), dim3(256), 0, stream>>>(
        state, dist,
        e1W1, e1b1, e1W2, e1b2,
        e2W1, e2b1, e2W2, e2b2,
        Wih0, Whh0, bih0, bhh0,
        Wih1, Whh1, bih1, bhh1,
        decW, decb, finW, finb, fin2W, fin2b,
        outp);
}

// Round 6
// 317.632 us; speedup vs baseline: 1.7817x; 1.6628x over previous
//
#include <hip/hip_runtime.h>

namespace {

constexpr int T_STEPS = 1000;
constexpr int NB      = 4096;
constexpr float LOG2E = 1.4426950408889634f;

typedef float v2f __attribute__((ext_vector_type(2)));

__device__ __forceinline__ float fexp2(float x) { return __builtin_amdgcn_exp2f(x); }
__device__ __forceinline__ float frcp(float x)  { return __builtin_amdgcn_rcpf(x); }

__device__ __forceinline__ v2f mkv2(float a, float b) { v2f r; r.x = a; r.y = b; return r; }

__device__ __forceinline__ v2f pkfma(v2f a, v2f b, v2f c) {
#if __has_builtin(__builtin_elementwise_fma)
    return __builtin_elementwise_fma(a, b, c);   // lowers to v_pk_fma_f32
#else
    v2f r; r.x = fmaf(a.x, b.x, c.x); r.y = fmaf(a.y, b.y, c.y); return r;
#endif
}

// DPP on the VALU pipe. row_ror 0x120|N rotates within each 16-lane row;
// quad_perm 0x00-0xFF permutes within quads. (All patterns HW-proven in R3.)
template<int CTRL>
__device__ __forceinline__ float dppf(float v) {
    int i = __float_as_int(v);
    return __int_as_float(__builtin_amdgcn_update_dpp(i, i, CTRL, 0xF, 0xF, false));
}

// W=16: one element per 16 lanes, 1024 waves = 1 wave/SIMD. Lane q: unit
// u=q&7, half hlf=q>>3; lane computes gate rows r0=hlf*16+u (i|g) and r1=r0+8
// (f|o). All cross-lane via DPP. Matvecs packed as v_pk_fma_f32 (v2f).
// x stream prefetched through a 4-step register ring (distance ~4 walls
// > HBM latency) so no step ever waits on its load.
__global__ __launch_bounds__(256, 1)
void lstm_fused_kernel(
    const float* __restrict__ state, const float* __restrict__ dist,
    const float* __restrict__ e1W1, const float* __restrict__ e1b1,
    const float* __restrict__ e1W2, const float* __restrict__ e1b2,
    const float* __restrict__ e2W1, const float* __restrict__ e2b1,
    const float* __restrict__ e2W2, const float* __restrict__ e2b2,
    const float* __restrict__ Wih0, const float* __restrict__ Whh0,
    const float* __restrict__ bih0, const float* __restrict__ bhh0,
    const float* __restrict__ Wih1, const float* __restrict__ Whh1,
    const float* __restrict__ bih1, const float* __restrict__ bhh1,
    const float* __restrict__ decW, const float* __restrict__ decb,
    const float* __restrict__ finW, const float* __restrict__ finb,
    const float* __restrict__ fin2W, const float* __restrict__ fin2b,
    float* __restrict__ out)
{
    const int tid = (int)threadIdx.x;
    const int q   = tid & 15;
    const int n   = blockIdx.x * 16 + (tid >> 4);
    const int u   = q & 7;
    const int hlf = q >> 3;
    const int r0  = hlf * 16 + u;   // row A (i_u | g_u)
    const int r1  = r0 + 8;         // row B (f_u | o_u)

    // probe row_ror direction once: slot k holds h[(u+sgn*k)&7]
    const int pv  = __builtin_amdgcn_update_dpp(0, q, 0x121, 0xF, 0xF, true);
    const int sgn = (pv == ((q + 1) & 15)) ? 1 : -1;
    auto pidx = [&](int k) { return (u + sgn * k) & 7; };

    const float sA   = hlf ? (-2.0f * LOG2E) : (-LOG2E);   // row A: sigmoid | tanh
    const float sB   = -LOG2E;                              // row B always sigmoid
    const float mulA = hlf ? 2.0f : 1.0f;
    const float addA = hlf ? -1.0f : 0.0f;

    // ---- packed weight rows (h-side permuted to rotated slot layout) ----
    v2f wx0a[4], wh0a[4], wx0b[4], wh0b[4];
    v2f wx1a[4], wh1a[4], wx1b[4], wh1b[4];
#pragma unroll
    for (int k = 0; k < 4; ++k) {
        const int k0 = 2 * k, k1 = 2 * k + 1;
        const int p0 = pidx(k0), p1 = pidx(k1);
        wx0a[k] = mkv2(Wih0[r0 * 8 + k0] * sA, Wih0[r0 * 8 + k1] * sA);
        wh0a[k] = mkv2(Whh0[r0 * 8 + p0] * sA, Whh0[r0 * 8 + p1] * sA);
        wx0b[k] = mkv2(Wih0[r1 * 8 + k0] * sB, Wih0[r1 * 8 + k1] * sB);
        wh0b[k] = mkv2(Whh0[r1 * 8 + p0] * sB, Whh0[r1 * 8 + p1] * sB);
        wx1a[k] = mkv2(Wih1[r0 * 8 + p0] * sA, Wih1[r0 * 8 + p1] * sA);
        wh1a[k] = mkv2(Whh1[r0 * 8 + p0] * sA, Whh1[r0 * 8 + p1] * sA);
        wx1b[k] = mkv2(Wih1[r1 * 8 + p0] * sB, Wih1[r1 * 8 + p1] * sB);
        wh1b[k] = mkv2(Whh1[r1 * 8 + p0] * sB, Whh1[r1 * 8 + p1] * sB);
    }
    const float bA0 = (bih0[r0] + bhh0[r0]) * sA, bB0 = (bih0[r1] + bhh0[r1]) * sB;
    const float bA1 = (bih1[r0] + bhh1[r0]) * sA, bB1 = (bih1[r1] + bhh1[r1]) * sB;

    // decoder: lane holds dec row dr=q&3 (slot-permuted); head row oo=u&3
    const int dr = q & 3;
    v2f dwr2[4];
#pragma unroll
    for (int k = 0; k < 4; ++k)
        dwr2[k] = mkv2(decW[dr * 8 + pidx(2 * k)], decW[dr * 8 + pidx(2 * k + 1)]);
    const float db = decb[dr];
    float fwp[4]; float fb;
    {
        const float* Wp = (u < 4) ? finW : fin2W;
        const float* bp = (u < 4) ? finb : fin2b;
        const int oo = u & 3;
#pragma unroll
        for (int jj = 0; jj < 4; ++jj) fwp[jj] = Wp[oo * 4 + ((dr + jj) & 3)];
        fb = bp[oo];
    }

    // ---------------- encoders (one-time, R3-verbatim) ----------------
    float h0s[8], h1s[8], c0, c1;
    {
        float s[16];
#pragma unroll
        for (int k = 0; k < 16; ++k) s[k] = state[n * 16 + k];
        float hm1[4], hm2[4];
#pragma unroll
        for (int m = 0; m < 4; ++m) {
            float a = e1b1[m], b = e2b1[m];
#pragma unroll
            for (int k = 0; k < 16; ++k) {
                a = fmaf(s[k], e1W1[m * 16 + k], a);
                b = fmaf(s[k], e2W1[m * 16 + k], b);
            }
            hm1[m] = fmaxf(a, 0.0f); hm2[m] = fmaxf(b, 0.0f);
        }
#pragma unroll
        for (int k = 0; k < 8; ++k) {
            const int p = pidx(k);
            float a = e1b2[p], b = e1b2[8 + p];
#pragma unroll
            for (int m = 0; m < 4; ++m) {
                a = fmaf(hm1[m], e1W2[p * 4 + m], a);
                b = fmaf(hm1[m], e1W2[(8 + p) * 4 + m], b);
            }
            h0s[k] = fmaxf(a, 0.0f);   // layer0 h init (slot layout)
            h1s[k] = fmaxf(b, 0.0f);   // layer1 h init
        }
        float a = e2b2[u], b = e2b2[8 + u];
#pragma unroll
        for (int m = 0; m < 4; ++m) {
            a = fmaf(hm2[m], e2W2[u * 4 + m], a);
            b = fmaf(hm2[m], e2W2[(8 + u) * 4 + m], b);
        }
        c0 = fmaxf(a, 0.0f);
        c1 = fmaxf(b, 0.0f);
    }
    v2f h0r0 = mkv2(h0s[0], h0s[1]), h0r1 = mkv2(h0s[2], h0s[3]);
    v2f h0r2 = mkv2(h0s[4], h0s[5]), h0r3 = mkv2(h0s[6], h0s[7]);
    v2f h1r0 = mkv2(h1s[0], h1s[1]), h1r1 = mkv2(h1s[2], h1s[3]);
    v2f h1r2 = mkv2(h1s[4], h1s[5]), h1r3 = mkv2(h1s[6], h1s[7]);

    // ---------------- x stream + output pointer ----------------
    const float4* dp = reinterpret_cast<const float4*>(dist) + (size_t)n * 2;
    constexpr size_t TS4 = (size_t)NB * 2;
    float* outp = out + ((u < 4) ? ((size_t)n * 4 + u)
                                 : ((size_t)T_STEPS * NB * 4 + (size_t)n * 4 + (u - 4)));
    const bool doStore = (q < 8);

    auto step = [&](const float4& lo, const float4& hi, float* op) {
        const v2f x0 = mkv2(lo.x, lo.y), x1 = mkv2(lo.z, lo.w);
        const v2f x2 = mkv2(hi.x, hi.y), x3 = mkv2(hi.z, hi.w);
        // ----- layer 0: two independent pk_fma chains per row; x terms first
        //       (ready early), h terms last (arrive at end of prev step) -----
        v2f pa = pkfma(x0, wx0a[0], mkv2(bA0, 0.0f));
        pa = pkfma(x1, wx0a[1], pa);
        pa = pkfma(h0r0, wh0a[0], pa);
        pa = pkfma(h0r1, wh0a[1], pa);
        v2f qa = pkfma(x2, wx0a[2], mkv2(0.0f, 0.0f));
        qa = pkfma(x3, wx0a[3], qa);
        qa = pkfma(h0r2, wh0a[2], qa);
        qa = pkfma(h0r3, wh0a[3], qa);
        v2f sa = pa + qa;
        const float A = sa.x + sa.y;
        v2f pb = pkfma(x0, wx0b[0], mkv2(bB0, 0.0f));
        pb = pkfma(x1, wx0b[1], pb);
        pb = pkfma(h0r0, wh0b[0], pb);
        pb = pkfma(h0r1, wh0b[1], pb);
        v2f qb = pkfma(x2, wx0b[2], mkv2(0.0f, 0.0f));
        qb = pkfma(x3, wx0b[3], qb);
        qb = pkfma(h0r2, wh0b[2], qb);
        qb = pkfma(h0r3, wh0b[3], qb);
        v2f sb = pb + qb;
        const float B = sb.x + sb.y;
        float a0 = fmaf(frcp(1.0f + fexp2(A)), mulA, addA);  // sig(i)|tanh(g)
        float a1 = frcp(1.0f + fexp2(B));                     // sig(f)|sig(o)
        float s0 = dppf<0x128>(a0);   // xor-8 partner
        float s1 = dppf<0x128>(a1);
        float prod = a0 * s0;         // sig(i)*tanh(g) on both halves
        float fg = hlf ? s1 : a1, og = hlf ? a1 : s1;
        c0 = fmaf(fg, c0, prod);
        float th = fmaf(frcp(1.0f + fexp2(c0 * (-2.0f * LOG2E))), 2.0f, -1.0f);
        float hn = og * th;
        {
            const float t1 = dppf<0x121>(hn), t2 = dppf<0x122>(hn), t3 = dppf<0x123>(hn);
            const float t4 = dppf<0x124>(hn), t5 = dppf<0x125>(hn), t6 = dppf<0x126>(hn);
            const float t7 = dppf<0x127>(hn);
            h0r0 = mkv2(hn, t1); h0r1 = mkv2(t2, t3);
            h0r2 = mkv2(t4, t5); h0r3 = mkv2(t6, t7);
        }
        // ----- layer 1: own-h chains first, fresh h0 terms last -----
        v2f pa1 = pkfma(h1r0, wh1a[0], mkv2(bA1, 0.0f));
        pa1 = pkfma(h1r1, wh1a[1], pa1);
        pa1 = pkfma(h0r0, wx1a[0], pa1);
        pa1 = pkfma(h0r1, wx1a[1], pa1);
        v2f qa1 = pkfma(h1r2, wh1a[2], mkv2(0.0f, 0.0f));
        qa1 = pkfma(h1r3, wh1a[3], qa1);
        qa1 = pkfma(h0r2, wx1a[2], qa1);
        qa1 = pkfma(h0r3, wx1a[3], qa1);
        v2f sa1 = pa1 + qa1;
        const float A1 = sa1.x + sa1.y;
        v2f pb1 = pkfma(h1r0, wh1b[0], mkv2(bB1, 0.0f));
        pb1 = pkfma(h1r1, wh1b[1], pb1);
        pb1 = pkfma(h0r0, wx1b[0], pb1);
        pb1 = pkfma(h0r1, wx1b[1], pb1);
        v2f qb1 = pkfma(h1r2, wh1b[2], mkv2(0.0f, 0.0f));
        qb1 = pkfma(h1r3, wh1b[3], qb1);
        qb1 = pkfma(h0r2, wx1b[2], qb1);
        qb1 = pkfma(h0r3, wx1b[3], qb1);
        v2f sb1 = pb1 + qb1;
        const float B1 = sb1.x + sb1.y;
        a0 = fmaf(frcp(1.0f + fexp2(A1)), mulA, addA);
        a1 = frcp(1.0f + fexp2(B1));
        s0 = dppf<0x128>(a0);
        s1 = dppf<0x128>(a1);
        prod = a0 * s0;
        fg = hlf ? s1 : a1; og = hlf ? a1 : s1;
        c1 = fmaf(fg, c1, prod);
        th = fmaf(frcp(1.0f + fexp2(c1 * (-2.0f * LOG2E))), 2.0f, -1.0f);
        hn = og * th;
        {
            const float t1 = dppf<0x121>(hn), t2 = dppf<0x122>(hn), t3 = dppf<0x123>(hn);
            const float t4 = dppf<0x124>(hn), t5 = dppf<0x125>(hn), t6 = dppf<0x126>(hn);
            const float t7 = dppf<0x127>(hn);
            h1r0 = mkv2(hn, t1); h1r1 = mkv2(t2, t3);
            h1r2 = mkv2(t4, t5); h1r3 = mkv2(t6, t7);
        }
        // ----- decoder + heads -----
        v2f dd = pkfma(h1r0, dwr2[0], mkv2(db, 0.0f));
        dd = pkfma(h1r1, dwr2[1], dd);
        v2f de = pkfma(h1r2, dwr2[2], mkv2(0.0f, 0.0f));
        de = pkfma(h1r3, dwr2[3], de);
        v2f dsum = dd + de;
        float da = fmaxf(dsum.x + dsum.y, 0.0f);
        const float d1 = dppf<0x39>(da);
        const float d2 = dppf<0x4E>(da);
        const float d3 = dppf<0x93>(da);
        float o = fb;
        o = fmaf(da, fwp[0], o); o = fmaf(d1, fwp[1], o);
        o = fmaf(d2, fwp[2], o); o = fmaf(d3, fwp[3], o);
        if (doStore) *op = o;
    };

    // ---- 4-step register prefetch ring (distance 4 steps > HBM latency) ----
    float4 r0a = dp[0],       r0b = dp[1];
    float4 r1a = dp[TS4],     r1b = dp[TS4 + 1];
    float4 r2a = dp[2 * TS4], r2b = dp[2 * TS4 + 1];
    float4 r3a = dp[3 * TS4], r3b = dp[3 * TS4 + 1];
    const float4* pf = dp + 4 * TS4;   // next load: t = 4

    // main loop: iters 0..248 consume steps 0..995 and load steps 4..999.
    for (int it = 0; it < 249; ++it) {
        float4 na, nb;
        na = pf[0]; nb = pf[1]; pf += TS4;
        step(r0a, r0b, outp); outp += (size_t)NB * 4;
        r0a = na; r0b = nb;
        na = pf[0]; nb = pf[1]; pf += TS4;
        step(r1a, r1b, outp); outp += (size_t)NB * 4;
        r1a = na; r1b = nb;
        na = pf[0]; nb = pf[1]; pf += TS4;
        step(r2a, r2b, outp); outp += (size_t)NB * 4;
        r2a = na; r2b = nb;
        na = pf[0]; nb = pf[1]; pf += TS4;
        step(r3a, r3b, outp); outp += (size_t)NB * 4;
        r3a = na; r3b = nb;
    }
    // tail: steps 996..999, no loads
    step(r0a, r0b, outp); outp += (size_t)NB * 4;
    step(r1a, r1b, outp); outp += (size_t)NB * 4;
    step(r2a, r2b, outp); outp += (size_t)NB * 4;
    step(r3a, r3b, outp);
}

} // namespace

extern "C" void kernel_launch(void* const* d_in, const int* in_sizes, int n_in,
                              void* d_out, int out_size, void* d_ws, size_t ws_size,
                              hipStream_t stream) {
    const float* state = (const float*)d_in[0];
    const float* dist  = (const float*)d_in[1];
    const float* e1W1  = (const float*)d_in[2];
    const float* e1b1  = (const float*)d_in[3];
    const float* e1W2  = (const float*)d_in[4];
    const float* e1b2  = (const float*)d_in[5];
    const float* e2W1  = (const float*)d_in[6];
    const float* e2b1  = (const float*)d_in[7];
    const float* e2W2  = (const float*)d_in[8];
    const float* e2b2  = (const float*)d_in[9];
    const float* Wih0  = (const float*)d_in[10];
    const float* Whh0  = (const float*)d_in[11];
    const float* bih0  = (const float*)d_in[12];
    const float* bhh0  = (const float*)d_in[13];
    const float* Wih1  = (const float*)d_in[14];
    const float* Whh1  = (const float*)d_in[15];
    const float* bih1  = (const float*)d_in[16];
    const float* bhh1  = (const float*)d_in[17];
    const float* decW  = (const float*)d_in[18];
    const float* decb  = (const float*)d_in[19];
    const float* finW  = (const float*)d_in[20];
    const float* finb  = (const float*)d_in[21];
    const float* fin2W = (const float*)d_in[22];
    const float* fin2b = (const float*)d_in[23];
    float* outp = (float*)d_out;

    lstm_fused_kernel<<<dim3(NB / 16), dim3(256), 0, stream>>>(
        state, dist,
        e1W1, e1b1, e1W2, e1b2,
        e2W1, e2b1, e2W2, e2b2,
        Wih0, Whh0, bih0, bhh0,
        Wih1, Whh1, bih1, bhh1,
        decW, decb, finW, finb, fin2W, fin2b,
        outp);
}